// Round 4
// baseline (110.911 us; speedup 1.0000x reference)
//
#include <hip/hip_runtime.h>

#define NTOK 16384
#define TB 8

typedef float f32x4_t __attribute__((ext_vector_type(4)));
typedef short s16x8_t __attribute__((ext_vector_type(8)));

__device__ __forceinline__ unsigned short f2bf(float f) {
    unsigned int x = __float_as_uint(f);
    x += 0x7fffu + ((x >> 16) & 1u);
    return (unsigned short)(x >> 16);
}
__device__ __forceinline__ float fexp2(float x) {
#if __has_builtin(__builtin_amdgcn_exp2f)
    return __builtin_amdgcn_exp2f(x);
#else
    return exp2f(x);
#endif
}
__device__ __forceinline__ float frcp(float x) {
#if __has_builtin(__builtin_amdgcn_rcpf)
    return __builtin_amdgcn_rcpf(x);
#else
    return 1.0f / x;
#endif
}
__device__ __forceinline__ float frsq(float x) {
#if __has_builtin(__builtin_amdgcn_rsqf)
    return __builtin_amdgcn_rsqf(x);
#else
    return rsqrtf(x);
#endif
}

// ---- prep: convert all weights to transposed bf16 [m][k] in d_ws ----
// layout (ushort): [0,16384)   W1T  [m=64][k=256]
//                  [16384+...] (st*5+q)*4096 : q=0 Wq,1 Wk,2 Wv,3 Wf1,4 Wf2, each [m=64][k=64]
__global__ __launch_bounds__(256)
void prep_kernel(const float* __restrict__ W1,
                 const float* __restrict__ Wq, const float* __restrict__ Wk,
                 const float* __restrict__ Wv, const float* __restrict__ Wf1,
                 const float* __restrict__ Wf2, unsigned short* __restrict__ wsb)
{
    const int i = blockIdx.x * 256 + threadIdx.x;
    if (i < 16384) {
        const int m = i >> 8, k = i & 255;
        wsb[i] = f2bf(W1[k * 64 + m]);
    } else if (i < 77824) {
        const int u  = i - 16384;
        const int mm = u >> 12;            // 0..14
        const int st = mm / 5, q = mm % 5;
        const int r  = u & 4095;
        const int m  = r >> 6, k = r & 63;
        const float* src = q == 0 ? Wq : q == 1 ? Wk : q == 2 ? Wv : q == 3 ? Wf1 : Wf2;
        wsb[i] = f2bf(src[st * 4096 + k * 64 + m]);
    }
}

__global__ __launch_bounds__(256, 8)
void tf3_kernel(const float* __restrict__ x,
                const float* __restrict__ b1,
                const float* __restrict__ bq, const float* __restrict__ bk,
                const float* __restrict__ bv,
                const float* __restrict__ bf1, const float* __restrict__ bf2,
                const float* __restrict__ lng, const float* __restrict__ lnb,
                const float* __restrict__ Wout, const float* __restrict__ bout,
                const unsigned short* __restrict__ wsb,
                float* __restrict__ out)
{
    // LDS ~14.8 KB -> 8 blocks/CU (wave-cap). Rows 8..15 of each fp32 tile are
    // the unused half of the 16-row MFMA; garbage there never reaches rows 0..7
    // (C row i depends only on A row i).
    __shared__ __align__(16) unsigned short a_lds[16 * 64];  // bf16 swizzled
    __shared__ __align__(16) float q_lds[16 * 68];
    __shared__ __align__(16) float ky_lds[16 * 68];
    __shared__ __align__(16) float v_lds[16 * 68];

    const int tid = threadIdx.x;
    const int wv  = tid >> 6;       // wave 0..3
    const int l   = tid & 63;       // lane
    const int n0  = blockIdx.x * TB;

    const int lr  = l & 15;         // A row / B,C col within 16
    const int q4  = l >> 4;         // k-quad / C row group
    const int c   = wv * 16 + lr;   // this wave-lane's output column

    // half-wave reduction geometry: half h owns token wv*2+h
    const int hh = l >> 5;
    const int e2 = l & 31;
    const int th = wv * 2 + hh;

    float res_reg[2], cur_reg[2];

    // ---------------- stage 0: h = x @ W1 + b1 (K=256, direct from global) ----------------
    {
        const float* xrow = x + (size_t)min(n0 + lr, NTOK - 1) * 256;
        f32x4_t acch = {0.f, 0.f, 0.f, 0.f};
        #pragma unroll
        for (int s5 = 0; s5 < 8; ++s5) {
            const int k0 = s5 * 32 + q4 * 8;
            const float4 u0 = *reinterpret_cast<const float4*>(xrow + k0);
            const float4 u1 = *reinterpret_cast<const float4*>(xrow + k0 + 4);
            s16x8_t af;
            af[0] = (short)f2bf(u0.x); af[1] = (short)f2bf(u0.y);
            af[2] = (short)f2bf(u0.z); af[3] = (short)f2bf(u0.w);
            af[4] = (short)f2bf(u1.x); af[5] = (short)f2bf(u1.y);
            af[6] = (short)f2bf(u1.z); af[7] = (short)f2bf(u1.w);
            const s16x8_t bf = *reinterpret_cast<const s16x8_t*>(&wsb[c * 256 + k0]);
            acch = __builtin_amdgcn_mfma_f32_16x16x32_bf16(af, bf, acch, 0, 0, 0);
        }
        const float bb = b1[c];
        #pragma unroll
        for (int rg = 0; rg < 4; ++rg)
            q_lds[(q4 * 4 + rg) * 68 + c] = acch[rg] + bb;
    }
    __syncthreads();
    #pragma unroll
    for (int tt = 0; tt < 2; ++tt) {     // cur = h, res = leaky(h, 0.1)
        const int t = wv * 2 + tt;
        const float h = q_lds[t * 68 + l];
        cur_reg[tt] = h;
        res_reg[tt] = h >= 0.f ? h : 0.1f * h;
        a_lds[t * 64 + (((l >> 3) ^ (t & 7)) * 8) + (l & 7)] = f2bf(h);
    }

    // ---------------- 3 attention stages ----------------
    for (int st = 0; st < 3; ++st) {
        const unsigned short* WS = wsb + 16384 + st * 5 * 4096;

        __syncthreads();                    // B1: a_lds(cur) ready
        // A-fragments (shared by Q,K,V GEMMs)
        const s16x8_t af0 = *reinterpret_cast<const s16x8_t*>(&a_lds[lr * 64 + ((q4       ^ (lr & 7)) * 8)]);
        const s16x8_t af1 = *reinterpret_cast<const s16x8_t*>(&a_lds[lr * 64 + (((4 + q4) ^ (lr & 7)) * 8)]);
        {   // Q
            const s16x8_t b0 = *reinterpret_cast<const s16x8_t*>(&WS[c * 64 + q4 * 8]);
            const s16x8_t b1f = *reinterpret_cast<const s16x8_t*>(&WS[c * 64 + 32 + q4 * 8]);
            f32x4_t acc = __builtin_amdgcn_mfma_f32_16x16x32_bf16(af0, b0, (f32x4_t){0.f,0.f,0.f,0.f}, 0, 0, 0);
            acc = __builtin_amdgcn_mfma_f32_16x16x32_bf16(af1, b1f, acc, 0, 0, 0);
            const float bb = bq[st * 64 + c];
            #pragma unroll
            for (int rg = 0; rg < 4; ++rg) q_lds[(q4 * 4 + rg) * 68 + c] = acc[rg] + bb;
        }
        {   // K
            const s16x8_t b0 = *reinterpret_cast<const s16x8_t*>(&WS[4096 + c * 64 + q4 * 8]);
            const s16x8_t b1f = *reinterpret_cast<const s16x8_t*>(&WS[4096 + c * 64 + 32 + q4 * 8]);
            f32x4_t acc = __builtin_amdgcn_mfma_f32_16x16x32_bf16(af0, b0, (f32x4_t){0.f,0.f,0.f,0.f}, 0, 0, 0);
            acc = __builtin_amdgcn_mfma_f32_16x16x32_bf16(af1, b1f, acc, 0, 0, 0);
            const float bb = bk[st * 64 + c];
            #pragma unroll
            for (int rg = 0; rg < 4; ++rg) ky_lds[(q4 * 4 + rg) * 68 + c] = acc[rg] + bb;
        }
        {   // V
            const s16x8_t b0 = *reinterpret_cast<const s16x8_t*>(&WS[8192 + c * 64 + q4 * 8]);
            const s16x8_t b1f = *reinterpret_cast<const s16x8_t*>(&WS[8192 + c * 64 + 32 + q4 * 8]);
            f32x4_t acc = __builtin_amdgcn_mfma_f32_16x16x32_bf16(af0, b0, (f32x4_t){0.f,0.f,0.f,0.f}, 0, 0, 0);
            acc = __builtin_amdgcn_mfma_f32_16x16x32_bf16(af1, b1f, acc, 0, 0, 0);
            const float bb = bv[st * 64 + c];
            #pragma unroll
            for (int rg = 0; rg < 4; ++rg) v_lds[(q4 * 4 + rg) * 68 + c] = acc[rg] + bb;
        }
        __syncthreads();                    // B2

        // ---- attention core ----
        float kmax_t[2], kmin_t[2];
        {   // half-wave k-range reduce for own token
            const float2 kv = *reinterpret_cast<const float2*>(&ky_lds[th * 68 + e2 * 2]);
            float kmx = fmaxf(kv.x, kv.y);
            float kmn = fminf(kv.x, kv.y);
            #pragma unroll
            for (int m = 1; m < 32; m <<= 1) {
                kmx = fmaxf(kmx, __shfl_xor(kmx, m, 64));
                kmn = fminf(kmn, __shfl_xor(kmn, m, 64));
            }
            #pragma unroll
            for (int tt = 0; tt < 2; ++tt) {
                kmax_t[tt] = __shfl(kmx, tt * 32, 64);
                kmin_t[tt] = __shfl(kmn, tt * 32, 64);
            }
        }
        #pragma unroll
        for (int tt = 0; tt < 2; ++tt) {
            const int t = wv * 2 + tt;
            const float qs = q_lds[t * 68 + l] * 1.44269504088896340736f;   // q*log2(e)
            const float m2 = fmaxf(qs * kmax_t[tt], qs * kmin_t[tt]);       // exact row max (rank-1)
            float s0 = 0.f, s1 = 0.f, p0 = 0.f, p1 = 0.f;
            #pragma unroll
            for (int j = 0; j < 64; j += 4) {
                const float4 kj = *reinterpret_cast<const float4*>(&ky_lds[t * 68 + j]); // uniform bcast
                const float4 vj = *reinterpret_cast<const float4*>(&v_lds[t * 68 + j]);
                const float e0 = fexp2(fmaf(qs, kj.x, -m2));
                const float e1 = fexp2(fmaf(qs, kj.y, -m2));
                const float e2v = fexp2(fmaf(qs, kj.z, -m2));
                const float e3 = fexp2(fmaf(qs, kj.w, -m2));
                s0 += e0 + e2v; s1 += e1 + e3;
                p0 = fmaf(e0, vj.x, p0); p1 = fmaf(e1, vj.y, p1);
                p0 = fmaf(e2v, vj.z, p0); p1 = fmaf(e3, vj.w, p1);
            }
            const float y = (p0 + p1) * frcp(s0 + s1) + cur_reg[tt];
            ky_lds[t * 68 + l] = y;   // overwrite K row (wave-private rows)
        }
        __syncthreads();                    // B3

        // ---- F1: h1 = leaky(Y @ Wf1 + bf1, 0.01) -> a_lds bf16 ----
        {
            f32x4_t acc = {0.f, 0.f, 0.f, 0.f};
            #pragma unroll
            for (int kh = 0; kh < 2; ++kh) {
                const float* yp = &ky_lds[lr * 68 + kh * 32 + q4 * 8];
                const float4 y0 = *reinterpret_cast<const float4*>(yp);
                const float4 y1 = *reinterpret_cast<const float4*>(yp + 4);
                s16x8_t af;
                af[0] = (short)f2bf(y0.x); af[1] = (short)f2bf(y0.y);
                af[2] = (short)f2bf(y0.z); af[3] = (short)f2bf(y0.w);
                af[4] = (short)f2bf(y1.x); af[5] = (short)f2bf(y1.y);
                af[6] = (short)f2bf(y1.z); af[7] = (short)f2bf(y1.w);
                const s16x8_t bf = *reinterpret_cast<const s16x8_t*>(&WS[3 * 4096 + c * 64 + kh * 32 + q4 * 8]);
                acc = __builtin_amdgcn_mfma_f32_16x16x32_bf16(af, bf, acc, 0, 0, 0);
            }
            const float bb = bf1[st * 64 + c];
            #pragma unroll
            for (int rg = 0; rg < 4; ++rg) {
                const int tr = q4 * 4 + rg;
                float h = acc[rg] + bb;
                h = h >= 0.f ? h : 0.01f * h;
                a_lds[tr * 64 + (((c >> 3) ^ (tr & 7)) * 8) + (c & 7)] = f2bf(h);
            }
        }
        __syncthreads();                    // B4

        // ---- F2: A = h1 @ Wf2 + bf2 + Y -> ky_lds ----
        {
            const s16x8_t ag0 = *reinterpret_cast<const s16x8_t*>(&a_lds[lr * 64 + ((q4       ^ (lr & 7)) * 8)]);
            const s16x8_t ag1 = *reinterpret_cast<const s16x8_t*>(&a_lds[lr * 64 + (((4 + q4) ^ (lr & 7)) * 8)]);
            const s16x8_t b0 = *reinterpret_cast<const s16x8_t*>(&WS[4 * 4096 + c * 64 + q4 * 8]);
            const s16x8_t b1f = *reinterpret_cast<const s16x8_t*>(&WS[4 * 4096 + c * 64 + 32 + q4 * 8]);
            f32x4_t acc = __builtin_amdgcn_mfma_f32_16x16x32_bf16(ag0, b0, (f32x4_t){0.f,0.f,0.f,0.f}, 0, 0, 0);
            acc = __builtin_amdgcn_mfma_f32_16x16x32_bf16(ag1, b1f, acc, 0, 0, 0);
            const float bb = bf2[st * 64 + c];
            #pragma unroll
            for (int rg = 0; rg < 4; ++rg) {
                const int tr = q4 * 4 + rg;
                ky_lds[tr * 68 + c] += acc[rg] + bb;
            }
        }
        __syncthreads();                    // B5

        // ---- LayerNorm (half-wave) + residual; stage cur as bf16 ----
        {
            const float2 av2 = *reinterpret_cast<const float2*>(&ky_lds[th * 68 + e2 * 2]);
            float ssum = av2.x + av2.y;
            #pragma unroll
            for (int m = 1; m < 32; m <<= 1) ssum += __shfl_xor(ssum, m, 64);
            const float mug = ssum * 0.015625f;
            const float d0 = av2.x - mug, d1 = av2.y - mug;
            float vsum = d0 * d0 + d1 * d1;
            #pragma unroll
            for (int m = 1; m < 32; m <<= 1) vsum += __shfl_xor(vsum, m, 64);
            const float lngv = lng[st * 64 + l];
            const float lnbv = lnb[st * 64 + l];
            #pragma unroll
            for (int tt = 0; tt < 2; ++tt) {
                const int t = wv * 2 + tt;
                const float mu = __shfl(mug, tt * 32, 64);
                const float vv = __shfl(vsum, tt * 32, 64);
                const float rs = frsq(vv * 0.015625f + 1e-5f);   // variance = vsum/64  (R3 bug: missing /64)
                const float a  = ky_lds[t * 68 + l];
                const float an = (a - mu) * rs * lngv + lnbv;
                const float rnew = res_reg[tt] + an;
                res_reg[tt] = rnew;
                cur_reg[tt] = rnew;
                a_lds[t * 64 + (((l >> 3) ^ (t & 7)) * 8) + (l & 7)] = f2bf(rnew);
            }
        }
    }

    // ---------------- head: leaky(res @ Wout + bout, 0.1), 5 output copies ----------------
    const float wo = Wout[l];
    const float bo = bout[0];
    #pragma unroll
    for (int tt = 0; tt < 2; ++tt)
        q_lds[(wv * 2 + tt) * 68 + l] = res_reg[tt] * wo;   // wave-private rows
    {
        const float2 pv = *reinterpret_cast<const float2*>(&q_lds[th * 68 + e2 * 2]);
        float p = pv.x + pv.y;
        #pragma unroll
        for (int m = 1; m < 32; m <<= 1) p += __shfl_xor(p, m, 64);
        if (e2 == 0) {
            float o = p + bo;
            o = o >= 0.f ? o : 0.1f * o;
            #pragma unroll
            for (int c5 = 0; c5 < 5; ++c5)
                out[(size_t)c5 * NTOK + n0 + th] = o;
        }
    }
}

extern "C" void kernel_launch(void* const* d_in, const int* in_sizes, int n_in,
                              void* d_out, int out_size, void* d_ws, size_t ws_size,
                              hipStream_t stream) {
    const float* x    = (const float*)d_in[0];
    const float* W1   = (const float*)d_in[1];
    const float* b1   = (const float*)d_in[2];
    const float* Wq   = (const float*)d_in[3];
    const float* bq   = (const float*)d_in[4];
    const float* Wk   = (const float*)d_in[5];
    const float* bk   = (const float*)d_in[6];
    const float* Wv   = (const float*)d_in[7];
    const float* bv   = (const float*)d_in[8];
    const float* Wf1  = (const float*)d_in[9];
    const float* bf1  = (const float*)d_in[10];
    const float* Wf2  = (const float*)d_in[11];
    const float* bf2  = (const float*)d_in[12];
    const float* lngp = (const float*)d_in[13];
    const float* lnbp = (const float*)d_in[14];
    const float* Wout = (const float*)d_in[15];
    const float* bout = (const float*)d_in[16];
    float* outp = (float*)d_out;
    unsigned short* wsb = (unsigned short*)d_ws;

    hipLaunchKernelGGL(prep_kernel, dim3(304), dim3(256), 0, stream,
                       W1, Wq, Wk, Wv, Wf1, Wf2, wsb);
    hipLaunchKernelGGL(tf3_kernel, dim3(NTOK / TB), dim3(256), 0, stream,
                       x, b1, bq, bk, bv, bf1, bf2, lngp, lnbp, Wout, bout,
                       (const unsigned short*)wsb, outp);
}

// Round 6
// 64.880 us; speedup vs baseline: 1.7095x; 1.7095x over previous
//
#include <hip/hip_runtime.h>

#define NTOK 16384
#define TB 16

typedef float f32x4_t __attribute__((ext_vector_type(4)));
typedef short s16x8_t __attribute__((ext_vector_type(8)));

__device__ __forceinline__ unsigned short f2bf(float f) {
    unsigned int x = __float_as_uint(f);
    x += 0x7fffu + ((x >> 16) & 1u);
    return (unsigned short)(x >> 16);
}
__device__ __forceinline__ float fexp2(float x) {
#if __has_builtin(__builtin_amdgcn_exp2f)
    return __builtin_amdgcn_exp2f(x);
#else
    return exp2f(x);
#endif
}
__device__ __forceinline__ float frcp(float x) {
#if __has_builtin(__builtin_amdgcn_rcpf)
    return __builtin_amdgcn_rcpf(x);
#else
    return 1.0f / x;
#endif
}
__device__ __forceinline__ float frsq(float x) {
#if __has_builtin(__builtin_amdgcn_rsqf)
    return __builtin_amdgcn_rsqf(x);
#else
    return rsqrtf(x);
#endif
}

// ---- prep (R4-proven): all weights transposed to bf16 [m][k] in d_ws ----
// ushort layout: [0,16384)  W1T [m=64][k=256]
//                16384 + (st*5+q)*4096 : q=0 Wq,1 Wk,2 Wv,3 Wf1,4 Wf2, each [m=64][k=64]
__global__ __launch_bounds__(256)
void prep_kernel(const float* __restrict__ W1,
                 const float* __restrict__ Wq, const float* __restrict__ Wk,
                 const float* __restrict__ Wv, const float* __restrict__ Wf1,
                 const float* __restrict__ Wf2, unsigned short* __restrict__ wsb)
{
    const int i = blockIdx.x * 256 + threadIdx.x;
    if (i < 16384) {
        const int m = i >> 8, k = i & 255;
        wsb[i] = f2bf(W1[k * 64 + m]);
    } else if (i < 77824) {
        const int u  = i - 16384;
        const int mi = u >> 12;            // 0..14
        const int st = mi / 5, q = mi % 5;
        const int r  = u & 4095;
        const int m  = r >> 6, k = r & 63;
        const float* src = q == 0 ? Wq : q == 1 ? Wk : q == 2 ? Wv : q == 3 ? Wf1 : Wf2;
        wsb[i] = f2bf(src[st * 4096 + k * 64 + m]);
    }
}

__global__ __launch_bounds__(256, 4)
void tf3_kernel(const float* __restrict__ x,
                const float* __restrict__ b1,
                const float* __restrict__ bq, const float* __restrict__ bk,
                const float* __restrict__ bv,
                const float* __restrict__ bf1, const float* __restrict__ bf2,
                const float* __restrict__ lng, const float* __restrict__ lnb,
                const float* __restrict__ Wout, const float* __restrict__ bout,
                const unsigned short* __restrict__ wsb,
                float* __restrict__ out)
{
    // LDS ~39.7 KB -> 4 blocks/CU. w3 slots are wave-partitioned: wave wv only
    // touches bytes [wv*2048, wv*2048+2048) of each 8 KB slot -> staging needs
    // no barriers (within-wave DS ordering only).
    __shared__ __align__(16) unsigned short w3_lds[3 * 4096]; // slots 0..2, bf16 swizzled
    __shared__ __align__(16) unsigned short a_lds[16 * 64];   // bf16 activations, swizzled
    __shared__ __align__(16) float q_lds[16 * 68];
    __shared__ __align__(16) float ky_lds[16 * 68];
    __shared__ __align__(16) float v_lds[16 * 68];

    const int tid = threadIdx.x;
    const int wv  = tid >> 6;        // wave 0..3
    const int l   = tid & 63;        // lane
    const int n0  = blockIdx.x * TB;

    const int lr  = l & 15;          // A row / B,C col within 16
    const int q4  = l >> 4;          // k-quad / C row group
    const int c   = wv * 16 + lr;    // this wave-lane's output column

    // 16-lane group reductions: group g owns token wv*4+g
    const int g  = q4;
    const int e  = lr;
    const int tg = wv * 4 + g;

    float res_reg[4], cur_reg[4];

    // ---- wave-partitioned weight staging (plain image -> swizzled LDS) ----
    auto LOAD2 = [&](int matIdx, s16x8_t& r0, s16x8_t& r1) {
        const char* gb = (const char*)(wsb + 16384 + matIdx * 4096) + wv * 2048 + l * 16;
        r0 = *reinterpret_cast<const s16x8_t*>(gb);           // coalesced 1KB/wave
        r1 = *reinterpret_cast<const s16x8_t*>(gb + 1024);
    };
    auto WRITE2 = [&](int slot, s16x8_t r0, s16x8_t r1) {
        #pragma unroll
        for (int p = 0; p < 2; ++p) {
            const int b  = wv * 2048 + p * 1024 + l * 16;     // byte off within slot (plain)
            const int mm = b >> 7;                            // row
            const int sw = ((b >> 4) & 7) ^ (mm & 7);         // swizzled chunk
            *reinterpret_cast<s16x8_t*>((char*)w3_lds + slot * 8192 + (b & ~127) + (sw << 4))
                = p ? r1 : r0;
        }
    };
    // one 16x16 output tile, K=64; A-frags passed in, B from swizzled slot
    auto mm16 = [&](s16x8_t af0, s16x8_t af1, const unsigned short* bbase) -> f32x4_t {
        const s16x8_t b0  = *reinterpret_cast<const s16x8_t*>(&bbase[c * 64 + (((0 + q4) ^ (c & 7)) * 8)]);
        const s16x8_t b1f = *reinterpret_cast<const s16x8_t*>(&bbase[c * 64 + (((4 + q4) ^ (c & 7)) * 8)]);
        f32x4_t acc = __builtin_amdgcn_mfma_f32_16x16x32_bf16(af0, b0, (f32x4_t){0.f,0.f,0.f,0.f}, 0, 0, 0);
        acc = __builtin_amdgcn_mfma_f32_16x16x32_bf16(af1, b1f, acc, 0, 0, 0);
        return acc;
    };

    s16x8_t wr0, wr1, wr2, wr3, wr4, wr5;      // staging registers

    // issue QKV(0) loads early (latency hides under stage0 GEMM)
    LOAD2(0, wr0, wr1); LOAD2(1, wr2, wr3); LOAD2(2, wr4, wr5);

    // ---------------- stage 0: h = x @ W1 + b1 (K=256, direct from global) ----------------
    {
        const float* xrow = x + (size_t)(n0 + lr) * 256;
        f32x4_t acch = {0.f, 0.f, 0.f, 0.f};
        #pragma unroll
        for (int s5 = 0; s5 < 8; ++s5) {
            const int k0 = s5 * 32 + q4 * 8;
            const float4 u0 = *reinterpret_cast<const float4*>(xrow + k0);
            const float4 u1 = *reinterpret_cast<const float4*>(xrow + k0 + 4);
            s16x8_t af;
            af[0] = (short)f2bf(u0.x); af[1] = (short)f2bf(u0.y);
            af[2] = (short)f2bf(u0.z); af[3] = (short)f2bf(u0.w);
            af[4] = (short)f2bf(u1.x); af[5] = (short)f2bf(u1.y);
            af[6] = (short)f2bf(u1.z); af[7] = (short)f2bf(u1.w);
            const s16x8_t bf = *reinterpret_cast<const s16x8_t*>(&wsb[c * 256 + k0]);
            acch = __builtin_amdgcn_mfma_f32_16x16x32_bf16(af, bf, acch, 0, 0, 0);
        }
        const float bb = b1[c];
        #pragma unroll
        for (int rg = 0; rg < 4; ++rg)
            q_lds[(q4 * 4 + rg) * 68 + c] = acch[rg] + bb;
    }
    // write staged QKV(0) into slots (wave-private; no barrier needed)
    WRITE2(0, wr0, wr1); WRITE2(1, wr2, wr3); WRITE2(2, wr4, wr5);
    __syncthreads();                       // B0: q_lds ready
    #pragma unroll
    for (int tt = 0; tt < 4; ++tt) {       // cur = h, res = leaky(h, 0.1)
        const int t = wv * 4 + tt;
        const float h = q_lds[t * 68 + l];
        cur_reg[tt] = h;
        res_reg[tt] = h >= 0.f ? h : 0.1f * h;
        a_lds[t * 64 + (((l >> 3) ^ (t & 7)) * 8) + (l & 7)] = f2bf(h);
    }

    // ---------------- 3 attention stages ----------------
    for (int st = 0; st < 3; ++st) {
        const float bqv  = bq[st * 64 + c];
        const float bkv  = bk[st * 64 + c];
        const float bvv  = bv[st * 64 + c];
        const float bf1v = bf1[st * 64 + c];
        const float bf2v = bf2[st * 64 + c];
        const float lngv = lng[st * 64 + l];
        const float lnbv = lnb[st * 64 + l];

        __syncthreads();                   // B1: a_lds ready (w3 is wave-private)
        {   // QKV: 3 GEMMs sharing A-fragments
            const s16x8_t af0 = *reinterpret_cast<const s16x8_t*>(&a_lds[lr * 64 + ((q4       ^ (lr & 7)) * 8)]);
            const s16x8_t af1 = *reinterpret_cast<const s16x8_t*>(&a_lds[lr * 64 + (((4 + q4) ^ (lr & 7)) * 8)]);
            f32x4_t aq = mm16(af0, af1, &w3_lds[0]);
            f32x4_t ak = mm16(af0, af1, &w3_lds[4096]);
            f32x4_t av = mm16(af0, af1, &w3_lds[8192]);
            #pragma unroll
            for (int rg = 0; rg < 4; ++rg) {
                const int tr = q4 * 4 + rg;
                q_lds[tr * 68 + c]  = aq[rg] + bqv;
                ky_lds[tr * 68 + c] = ak[rg] + bkv;
                v_lds[tr * 68 + c]  = av[rg] + bvv;
            }
        }
        // issue F-weight loads (slots consumed above; latency hides under attention)
        LOAD2(st * 5 + 3, wr0, wr1);
        LOAD2(st * 5 + 4, wr2, wr3);
        __syncthreads();                   // B2

        // ---- attention core ----
        float kmax_t[4], kmin_t[4];
        {   // group g reduces token tg's K row
            const float4 kv = *reinterpret_cast<const float4*>(&ky_lds[tg * 68 + e * 4]);
            float kmx = fmaxf(fmaxf(kv.x, kv.y), fmaxf(kv.z, kv.w));
            float kmn = fminf(fminf(kv.x, kv.y), fminf(kv.z, kv.w));
            #pragma unroll
            for (int m = 1; m < 16; m <<= 1) {
                kmx = fmaxf(kmx, __shfl_xor(kmx, m, 64));
                kmn = fminf(kmn, __shfl_xor(kmn, m, 64));
            }
            #pragma unroll
            for (int tt = 0; tt < 4; ++tt) {
                kmax_t[tt] = __shfl(kmx, tt * 16, 64);
                kmin_t[tt] = __shfl(kmn, tt * 16, 64);
            }
        }
        #pragma unroll
        for (int tt = 0; tt < 4; ++tt) {
            const int t = wv * 4 + tt;
            const float qs = q_lds[t * 68 + l] * 1.44269504088896340736f;  // q*log2(e)
            const float m2 = fmaxf(qs * kmax_t[tt], qs * kmin_t[tt]);      // exact row max (rank-1)
            float s0 = 0.f, s1 = 0.f, p0 = 0.f, p1 = 0.f;
            #pragma unroll
            for (int j = 0; j < 64; j += 4) {
                const float4 kj = *reinterpret_cast<const float4*>(&ky_lds[t * 68 + j]); // uniform bcast
                const float4 vj = *reinterpret_cast<const float4*>(&v_lds[t * 68 + j]);
                const float e0 = fexp2(fmaf(qs, kj.x, -m2));
                const float e1 = fexp2(fmaf(qs, kj.y, -m2));
                const float e2v = fexp2(fmaf(qs, kj.z, -m2));
                const float e3 = fexp2(fmaf(qs, kj.w, -m2));
                s0 += e0 + e2v; s1 += e1 + e3;
                p0 = fmaf(e0, vj.x, p0); p1 = fmaf(e1, vj.y, p1);
                p0 = fmaf(e2v, vj.z, p0); p1 = fmaf(e3, vj.w, p1);
            }
            const float y = (p0 + p1) * frcp(s0 + s1) + cur_reg[tt];
            ky_lds[t * 68 + l] = y;        // overwrite K row (wave-private rows)
        }
        __syncthreads();                   // B3

        // commit F weights to slots 0/1 (own rows; vmcnt latency already covered)
        WRITE2(0, wr0, wr1); WRITE2(1, wr2, wr3);

        // ---- F1: h1 = leaky(Y @ Wf1 + bf1, 0.01) -> a_lds bf16 ----
        {
            f32x4_t acc = {0.f, 0.f, 0.f, 0.f};
            #pragma unroll
            for (int kh = 0; kh < 2; ++kh) {
                const float* yp = &ky_lds[lr * 68 + kh * 32 + q4 * 8];
                const float4 y0 = *reinterpret_cast<const float4*>(yp);
                const float4 y1 = *reinterpret_cast<const float4*>(yp + 4);
                s16x8_t af;
                af[0] = (short)f2bf(y0.x); af[1] = (short)f2bf(y0.y);
                af[2] = (short)f2bf(y0.z); af[3] = (short)f2bf(y0.w);
                af[4] = (short)f2bf(y1.x); af[5] = (short)f2bf(y1.y);
                af[6] = (short)f2bf(y1.z); af[7] = (short)f2bf(y1.w);
                const int ck = kh * 4 + q4;
                const s16x8_t bf = *reinterpret_cast<const s16x8_t*>(&w3_lds[c * 64 + ((ck ^ (c & 7)) * 8)]);
                acc = __builtin_amdgcn_mfma_f32_16x16x32_bf16(af, bf, acc, 0, 0, 0);
            }
            #pragma unroll
            for (int rg = 0; rg < 4; ++rg) {
                const int tr = q4 * 4 + rg;
                float h = acc[rg] + bf1v;
                h = h >= 0.f ? h : 0.01f * h;
                a_lds[tr * 64 + (((c >> 3) ^ (tr & 7)) * 8) + (c & 7)] = f2bf(h);
            }
        }
        // issue next-stage QKV loads (latency hides under F2 + LN)
        if (st < 2) {
            LOAD2((st + 1) * 5 + 0, wr0, wr1);
            LOAD2((st + 1) * 5 + 1, wr2, wr3);
            LOAD2((st + 1) * 5 + 2, wr4, wr5);
        }
        __syncthreads();                   // B4

        // ---- F2: A = h1 @ Wf2 + bf2 + Y -> ky_lds ----
        {
            const s16x8_t ag0 = *reinterpret_cast<const s16x8_t*>(&a_lds[lr * 64 + ((q4       ^ (lr & 7)) * 8)]);
            const s16x8_t ag1 = *reinterpret_cast<const s16x8_t*>(&a_lds[lr * 64 + (((4 + q4) ^ (lr & 7)) * 8)]);
            f32x4_t acc = mm16(ag0, ag1, &w3_lds[4096]);
            #pragma unroll
            for (int rg = 0; rg < 4; ++rg) {
                const int tr = q4 * 4 + rg;
                ky_lds[tr * 68 + c] += acc[rg] + bf2v;
            }
        }
        __syncthreads();                   // B5

        // ---- LayerNorm (16-lane groups) + residual; stage cur as bf16 ----
        {
            const float4 av4 = *reinterpret_cast<const float4*>(&ky_lds[tg * 68 + e * 4]);
            float ssum = av4.x + av4.y + av4.z + av4.w;
            #pragma unroll
            for (int m = 1; m < 16; m <<= 1) ssum += __shfl_xor(ssum, m, 64);
            const float mug = ssum * 0.015625f;
            const float d0 = av4.x - mug, d1 = av4.y - mug, d2 = av4.z - mug, d3 = av4.w - mug;
            float vsum = d0 * d0 + d1 * d1 + d2 * d2 + d3 * d3;
            #pragma unroll
            for (int m = 1; m < 16; m <<= 1) vsum += __shfl_xor(vsum, m, 64);
            #pragma unroll
            for (int tt = 0; tt < 4; ++tt) {
                const int t = wv * 4 + tt;
                const float mu = __shfl(mug, tt * 16, 64);
                const float vv = __shfl(vsum, tt * 16, 64);
                const float rs = frsq(vv * 0.015625f + 1e-5f);   // variance = vsum/64
                const float a  = ky_lds[t * 68 + l];
                const float an = (a - mu) * rs * lngv + lnbv;
                const float rnew = res_reg[tt] + an;
                res_reg[tt] = rnew;
                cur_reg[tt] = rnew;
                a_lds[t * 64 + (((l >> 3) ^ (t & 7)) * 8) + (l & 7)] = f2bf(rnew);
            }
        }
        // commit next-stage QKV (own rows; slots 0/1 done at F1/F2, slot 2 at QKV)
        if (st < 2) { WRITE2(0, wr0, wr1); WRITE2(1, wr2, wr3); WRITE2(2, wr4, wr5); }
    }

    // ---------------- head: leaky(res @ Wout + bout, 0.1), 5 output copies ----------------
    const float wo = Wout[l];
    const float bo = bout[0];
    #pragma unroll
    for (int tt = 0; tt < 4; ++tt)
        q_lds[(wv * 4 + tt) * 68 + l] = res_reg[tt] * wo;   // wave-private rows
    {
        const float4 pv = *reinterpret_cast<const float4*>(&q_lds[tg * 68 + e * 4]);
        float p = pv.x + pv.y + pv.z + pv.w;
        #pragma unroll
        for (int m = 1; m < 16; m <<= 1) p += __shfl_xor(p, m, 64);
        if (e == 0) {
            float o = p + bo;
            o = o >= 0.f ? o : 0.1f * o;
            #pragma unroll
            for (int c5 = 0; c5 < 5; ++c5)
                out[(size_t)c5 * NTOK + n0 + tg] = o;
        }
    }
}

extern "C" void kernel_launch(void* const* d_in, const int* in_sizes, int n_in,
                              void* d_out, int out_size, void* d_ws, size_t ws_size,
                              hipStream_t stream) {
    const float* x    = (const float*)d_in[0];
    const float* W1   = (const float*)d_in[1];
    const float* b1   = (const float*)d_in[2];
    const float* Wq   = (const float*)d_in[3];
    const float* bq   = (const float*)d_in[4];
    const float* Wk   = (const float*)d_in[5];
    const float* bk   = (const float*)d_in[6];
    const float* Wv   = (const float*)d_in[7];
    const float* bv   = (const float*)d_in[8];
    const float* Wf1  = (const float*)d_in[9];
    const float* bf1  = (const float*)d_in[10];
    const float* Wf2  = (const float*)d_in[11];
    const float* bf2  = (const float*)d_in[12];
    const float* lngp = (const float*)d_in[13];
    const float* lnbp = (const float*)d_in[14];
    const float* Wout = (const float*)d_in[15];
    const float* bout = (const float*)d_in[16];
    float* outp = (float*)d_out;
    unsigned short* wsb = (unsigned short*)d_ws;

    hipLaunchKernelGGL(prep_kernel, dim3(304), dim3(256), 0, stream,
                       W1, Wq, Wk, Wv, Wf1, Wf2, wsb);
    hipLaunchKernelGGL(tf3_kernel, dim3(NTOK / TB), dim3(256), 0, stream,
                       x, b1, bq, bk, bv, bf1, bf2, lngp, lnbp, Wout, bout,
                       (const unsigned short*)wsb, outp);
}

// Round 8
// 57.404 us; speedup vs baseline: 1.9321x; 1.1302x over previous
//
#include <hip/hip_runtime.h>

#define NTOK 16384
#define TB 16

typedef float f32x4_t __attribute__((ext_vector_type(4)));
typedef short s16x8_t __attribute__((ext_vector_type(8)));

union bfpack { unsigned int u[4]; s16x8_t v; };

__device__ __forceinline__ unsigned int pk2bf(float lo, float hi) {
    unsigned int r;
    asm("v_cvt_pk_bf16_f32 %0, %1, %2" : "=v"(r) : "v"(lo), "v"(hi));
    return r;
}
__device__ __forceinline__ unsigned short f2bf(float f) {   // 1-instr scalar (RNE)
    unsigned int r;
    asm("v_cvt_pk_bf16_f32 %0, %1, %1" : "=v"(r) : "v"(f));
    return (unsigned short)r;
}
__device__ __forceinline__ unsigned short f2bf_host_style(float f) {  // prep (proven path)
    unsigned int x = __float_as_uint(f);
    x += 0x7fffu + ((x >> 16) & 1u);
    return (unsigned short)(x >> 16);
}
__device__ __forceinline__ float fexp2(float x) {
#if __has_builtin(__builtin_amdgcn_exp2f)
    return __builtin_amdgcn_exp2f(x);
#else
    return exp2f(x);
#endif
}
__device__ __forceinline__ float frcp(float x) {
#if __has_builtin(__builtin_amdgcn_rcpf)
    return __builtin_amdgcn_rcpf(x);
#else
    return 1.0f / x;
#endif
}
__device__ __forceinline__ float frsq(float x) {
#if __has_builtin(__builtin_amdgcn_rsqf)
    return __builtin_amdgcn_rsqf(x);
#else
    return rsqrtf(x);
#endif
}

// ---- prep (R4/R6-proven): all weights transposed to bf16 [m][k] in d_ws ----
// ushort layout: [0,16384)  W1T [m=64][k=256]
//                16384 + (st*5+q)*4096 : q=0 Wq,1 Wk,2 Wv,3 Wf1,4 Wf2, each [m=64][k=64]
__global__ __launch_bounds__(256)
void prep_kernel(const float* __restrict__ W1,
                 const float* __restrict__ Wq, const float* __restrict__ Wk,
                 const float* __restrict__ Wv, const float* __restrict__ Wf1,
                 const float* __restrict__ Wf2, unsigned short* __restrict__ wsb)
{
    const int i = blockIdx.x * 256 + threadIdx.x;
    if (i < 16384) {
        const int m = i >> 8, k = i & 255;
        wsb[i] = f2bf_host_style(W1[k * 64 + m]);
    } else if (i < 77824) {
        const int u  = i - 16384;
        const int mi = u >> 12;            // 0..14
        const int st = mi / 5, q = mi % 5;
        const int r  = u & 4095;
        const int m  = r >> 6, k = r & 63;
        const float* src = q == 0 ? Wq : q == 1 ? Wk : q == 2 ? Wv : q == 3 ? Wf1 : Wf2;
        wsb[i] = f2bf_host_style(src[st * 4096 + k * 64 + m]);
    }
}

__global__ __launch_bounds__(256, 4)
void tf3_kernel(const float* __restrict__ x,
                const float* __restrict__ b1,
                const float* __restrict__ bq, const float* __restrict__ bk,
                const float* __restrict__ bv,
                const float* __restrict__ bf1, const float* __restrict__ bf2,
                const float* __restrict__ lng, const float* __restrict__ lnb,
                const float* __restrict__ Wout, const float* __restrict__ bout,
                const unsigned short* __restrict__ wsb,
                float* __restrict__ out)
{
    // LDS ~39.9 KB -> 4 blocks/CU. w3 slots wave-partitioned -> staging barrier-free.
    // During stage0, w3[0..8KB) temporarily holds the bf16 x-image.
    __shared__ __align__(16) unsigned short w3_lds[3 * 4096];
    __shared__ __align__(16) unsigned short a_lds[16 * 64];
    __shared__ __align__(16) float q_lds[16 * 68];
    __shared__ __align__(16) float ky_lds[16 * 68];
    __shared__ __align__(16) float v_lds[16 * 68];

    const int tid = threadIdx.x;
    const int wv  = tid >> 6;        // wave 0..3
    const int l   = tid & 63;        // lane
    const int n0  = blockIdx.x * TB;

    const int lr  = l & 15;          // A row / B,C col within 16
    const int q4  = l >> 4;          // k-quad / C row group
    const int c   = wv * 16 + lr;    // this wave-lane's output column

    const int ge = lr;               // 16-lane group elem
    const int tg = wv * 4 + q4;      // group-owned token

    float res_reg[4], cur_reg[4];

    auto LOAD2 = [&](int matIdx, s16x8_t& r0, s16x8_t& r1) {
        const char* gb = (const char*)(wsb + 16384 + matIdx * 4096) + wv * 2048 + l * 16;
        r0 = *reinterpret_cast<const s16x8_t*>(gb);
        r1 = *reinterpret_cast<const s16x8_t*>(gb + 1024);
    };
    auto WRITE2 = [&](int slot, s16x8_t r0, s16x8_t r1) {
        #pragma unroll
        for (int p = 0; p < 2; ++p) {
            const int b  = wv * 2048 + p * 1024 + l * 16;
            const int mm = b >> 7;
            const int sw = ((b >> 4) & 7) ^ (mm & 7);
            *reinterpret_cast<s16x8_t*>((char*)w3_lds + slot * 8192 + (b & ~127) + (sw << 4))
                = p ? r1 : r0;
        }
    };
    auto mm16 = [&](s16x8_t af0, s16x8_t af1, const unsigned short* bbase) -> f32x4_t {
        const s16x8_t b0  = *reinterpret_cast<const s16x8_t*>(&bbase[c * 64 + (((0 + q4) ^ (c & 7)) * 8)]);
        const s16x8_t b1f = *reinterpret_cast<const s16x8_t*>(&bbase[c * 64 + (((4 + q4) ^ (c & 7)) * 8)]);
        f32x4_t acc = __builtin_amdgcn_mfma_f32_16x16x32_bf16(af0, b0, (f32x4_t){0.f,0.f,0.f,0.f}, 0, 0, 0);
        acc = __builtin_amdgcn_mfma_f32_16x16x32_bf16(af1, b1f, acc, 0, 0, 0);
        return acc;
    };

    s16x8_t wr0, wr1, wr2, wr3, wr4, wr5;

    // issue QKV(0) weight loads early
    LOAD2(0, wr0, wr1); LOAD2(1, wr2, wr3); LOAD2(2, wr4, wr5);

    // ---- shared x-convert: 16 f2bf/thread -> swizzled bf16 image in w3[0..8KB) ----
    {
        const int r  = tid & 15;           // token row
        const int cb = tid >> 4;           // 16-col block 0..15
        const float* xp = x + (size_t)(n0 + r) * 256 + cb * 16;
        const float4 u0 = *reinterpret_cast<const float4*>(xp);
        const float4 u1 = *reinterpret_cast<const float4*>(xp + 4);
        const float4 u2 = *reinterpret_cast<const float4*>(xp + 8);
        const float4 u3 = *reinterpret_cast<const float4*>(xp + 12);
        bfpack P0, P1;
        P0.u[0] = pk2bf(u0.x, u0.y); P0.u[1] = pk2bf(u0.z, u0.w);
        P0.u[2] = pk2bf(u1.x, u1.y); P0.u[3] = pk2bf(u1.z, u1.w);
        P1.u[0] = pk2bf(u2.x, u2.y); P1.u[1] = pk2bf(u2.z, u2.w);
        P1.u[2] = pk2bf(u3.x, u3.y); P1.u[3] = pk2bf(u3.z, u3.w);
        char* rowb = (char*)w3_lds + r * 512;
        *reinterpret_cast<s16x8_t*>(rowb + (((cb * 2    ) ^ (r & 7)) << 4)) = P0.v;
        *reinterpret_cast<s16x8_t*>(rowb + (((cb * 2 + 1) ^ (r & 7)) << 4)) = P1.v;
    }
    __syncthreads();                       // B0a: x-image ready

    // ---- stage 0: h = x @ W1 + b1 (A from LDS image, B direct from global W1T) ----
    {
        f32x4_t acch = {0.f, 0.f, 0.f, 0.f};
        #pragma unroll
        for (int s5 = 0; s5 < 8; ++s5) {
            const s16x8_t af = *reinterpret_cast<const s16x8_t*>(
                (const char*)w3_lds + lr * 512 + ((((s5 * 4 + q4)) ^ (lr & 7)) << 4));
            const s16x8_t bf = *reinterpret_cast<const s16x8_t*>(&wsb[c * 256 + s5 * 32 + q4 * 8]);
            acch = __builtin_amdgcn_mfma_f32_16x16x32_bf16(af, bf, acch, 0, 0, 0);
        }
        const float bb = b1[c];
        #pragma unroll
        for (int rg = 0; rg < 4; ++rg)
            q_lds[(q4 * 4 + rg) * 68 + c] = acch[rg] + bb;
    }
    __syncthreads();                       // B0b: x-image consumed + q_lds ready
    WRITE2(0, wr0, wr1); WRITE2(1, wr2, wr3); WRITE2(2, wr4, wr5);
    #pragma unroll
    for (int tt = 0; tt < 4; ++tt) {       // cur = h, res = leaky(h, 0.1)
        const int t = wv * 4 + tt;
        const float h = q_lds[t * 68 + l];
        cur_reg[tt] = h;
        res_reg[tt] = h >= 0.f ? h : 0.1f * h;
        a_lds[t * 64 + (((l >> 3) ^ (t & 7)) * 8) + (l & 7)] = f2bf(h);
    }

    // ---------------- 3 attention stages ----------------
    for (int st = 0; st < 3; ++st) {
        const float bqv  = bq[st * 64 + c];
        const float bkv  = bk[st * 64 + c];
        const float bvv  = bv[st * 64 + c];
        const float bf1v = bf1[st * 64 + c];
        const float bf2v = bf2[st * 64 + c];
        const float lngv = lng[st * 64 + l];
        const float lnbv = lnb[st * 64 + l];

        __syncthreads();                   // B1: a_lds ready
        {   // QKV: 3 GEMMs sharing A-fragments
            const s16x8_t af0 = *reinterpret_cast<const s16x8_t*>(&a_lds[lr * 64 + ((q4       ^ (lr & 7)) * 8)]);
            const s16x8_t af1 = *reinterpret_cast<const s16x8_t*>(&a_lds[lr * 64 + (((4 + q4) ^ (lr & 7)) * 8)]);
            f32x4_t aq = mm16(af0, af1, &w3_lds[0]);
            f32x4_t ak = mm16(af0, af1, &w3_lds[4096]);
            f32x4_t av = mm16(af0, af1, &w3_lds[8192]);
            #pragma unroll
            for (int rg = 0; rg < 4; ++rg) {
                const int tr = q4 * 4 + rg;
                q_lds[tr * 68 + c]  = aq[rg] + bqv;
                ky_lds[tr * 68 + c] = ak[rg] + bkv;
                v_lds[tr * 68 + c]  = av[rg] + bvv;
            }
        }
        // issue F-weight loads
        LOAD2(st * 5 + 3, wr0, wr1);
        LOAD2(st * 5 + 4, wr2, wr3);
        __syncthreads();                   // B2

        // ---- attention core (R6-proven kmax/kmin group reduce -> exact row max) ----
        float kmax_t[4], kmin_t[4];
        {   // group g reduces token tg's K row
            const float4 kv = *reinterpret_cast<const float4*>(&ky_lds[tg * 68 + ge * 4]);
            float kmx = fmaxf(fmaxf(kv.x, kv.y), fmaxf(kv.z, kv.w));
            float kmn = fminf(fminf(kv.x, kv.y), fminf(kv.z, kv.w));
            #pragma unroll
            for (int m = 1; m < 16; m <<= 1) {
                kmx = fmaxf(kmx, __shfl_xor(kmx, m, 64));
                kmn = fminf(kmn, __shfl_xor(kmn, m, 64));
            }
            #pragma unroll
            for (int tt = 0; tt < 4; ++tt) {
                kmax_t[tt] = __shfl(kmx, tt * 16, 64);
                kmin_t[tt] = __shfl(kmn, tt * 16, 64);
            }
        }
        #pragma unroll
        for (int tt = 0; tt < 4; ++tt) {
            const int t = wv * 4 + tt;
            const float qs = q_lds[t * 68 + l] * 1.44269504088896340736f;   // q*log2(e)
            const float m2 = fmaxf(qs * kmax_t[tt], qs * kmin_t[tt]);       // exact row max (rank-1)
            const float* kb = &ky_lds[t * 68];
            const float* vb = &v_lds[t * 68];
            float4 ka0 = *reinterpret_cast<const float4*>(kb);
            float4 ka1 = *reinterpret_cast<const float4*>(kb + 4);
            float4 va0 = *reinterpret_cast<const float4*>(vb);
            float4 va1 = *reinterpret_cast<const float4*>(vb + 4);
            float s0 = 0.f, s1 = 0.f, p0 = 0.f, p1 = 0.f;
            #pragma unroll
            for (int j = 0; j < 64; j += 8) {
                float4 kn0, kn1, vn0, vn1;
                if (j < 56) {              // prefetch next 8-chunk
                    kn0 = *reinterpret_cast<const float4*>(kb + j + 8);
                    kn1 = *reinterpret_cast<const float4*>(kb + j + 12);
                    vn0 = *reinterpret_cast<const float4*>(vb + j + 8);
                    vn1 = *reinterpret_cast<const float4*>(vb + j + 12);
                }
                const float e0 = fexp2(fmaf(qs, ka0.x, -m2)); s0 += e0; p0 = fmaf(e0, va0.x, p0);
                const float e1 = fexp2(fmaf(qs, ka0.y, -m2)); s1 += e1; p1 = fmaf(e1, va0.y, p1);
                const float e2 = fexp2(fmaf(qs, ka0.z, -m2)); s0 += e2; p0 = fmaf(e2, va0.z, p0);
                const float e3 = fexp2(fmaf(qs, ka0.w, -m2)); s1 += e3; p1 = fmaf(e3, va0.w, p1);
                const float e4 = fexp2(fmaf(qs, ka1.x, -m2)); s0 += e4; p0 = fmaf(e4, va1.x, p0);
                const float e5 = fexp2(fmaf(qs, ka1.y, -m2)); s1 += e5; p1 = fmaf(e5, va1.y, p1);
                const float e6 = fexp2(fmaf(qs, ka1.z, -m2)); s0 += e6; p0 = fmaf(e6, va1.z, p0);
                const float e7 = fexp2(fmaf(qs, ka1.w, -m2)); s1 += e7; p1 = fmaf(e7, va1.w, p1);
                ka0 = kn0; ka1 = kn1; va0 = vn0; va1 = vn1;
            }
            const float y = (p0 + p1) * frcp(s0 + s1) + cur_reg[tt];
            ky_lds[t * 68 + l] = y;        // overwrite K row (wave-private rows)
        }
        __syncthreads();                   // B3

        WRITE2(0, wr0, wr1); WRITE2(1, wr2, wr3);

        // ---- F1: h1 = leaky(Y @ Wf1 + bf1, 0.01) -> a_lds bf16 ----
        {
            f32x4_t acc = {0.f, 0.f, 0.f, 0.f};
            #pragma unroll
            for (int kh = 0; kh < 2; ++kh) {
                const float* yp = &ky_lds[lr * 68 + kh * 32 + q4 * 8];
                const float4 y0 = *reinterpret_cast<const float4*>(yp);
                const float4 y1 = *reinterpret_cast<const float4*>(yp + 4);
                bfpack P;
                P.u[0] = pk2bf(y0.x, y0.y); P.u[1] = pk2bf(y0.z, y0.w);
                P.u[2] = pk2bf(y1.x, y1.y); P.u[3] = pk2bf(y1.z, y1.w);
                const int ck = kh * 4 + q4;
                const s16x8_t bf = *reinterpret_cast<const s16x8_t*>(&w3_lds[c * 64 + ((ck ^ (c & 7)) * 8)]);
                acc = __builtin_amdgcn_mfma_f32_16x16x32_bf16(P.v, bf, acc, 0, 0, 0);
            }
            #pragma unroll
            for (int rg = 0; rg < 4; ++rg) {
                const int tr = q4 * 4 + rg;
                float h = acc[rg] + bf1v;
                h = h >= 0.f ? h : 0.01f * h;
                a_lds[tr * 64 + (((c >> 3) ^ (tr & 7)) * 8) + (c & 7)] = f2bf(h);
            }
        }
        if (st < 2) {
            LOAD2((st + 1) * 5 + 0, wr0, wr1);
            LOAD2((st + 1) * 5 + 1, wr2, wr3);
            LOAD2((st + 1) * 5 + 2, wr4, wr5);
        }
        __syncthreads();                   // B4

        // ---- F2: A = h1 @ Wf2 + bf2 + Y -> ky_lds ----
        {
            const s16x8_t ag0 = *reinterpret_cast<const s16x8_t*>(&a_lds[lr * 64 + ((q4       ^ (lr & 7)) * 8)]);
            const s16x8_t ag1 = *reinterpret_cast<const s16x8_t*>(&a_lds[lr * 64 + (((4 + q4) ^ (lr & 7)) * 8)]);
            f32x4_t acc = mm16(ag0, ag1, &w3_lds[4096]);
            #pragma unroll
            for (int rg = 0; rg < 4; ++rg) {
                const int tr = q4 * 4 + rg;
                ky_lds[tr * 68 + c] += acc[rg] + bf2v;
            }
        }
        __syncthreads();                   // B5

        // ---- LayerNorm (16-lane groups) + residual; stage cur as bf16 ----
        {
            const float4 av4 = *reinterpret_cast<const float4*>(&ky_lds[tg * 68 + ge * 4]);
            float ssum = av4.x + av4.y + av4.z + av4.w;
            #pragma unroll
            for (int m = 1; m < 16; m <<= 1) ssum += __shfl_xor(ssum, m, 64);
            const float mug = ssum * 0.015625f;
            const float d0 = av4.x - mug, d1 = av4.y - mug, d2 = av4.z - mug, d3 = av4.w - mug;
            float vsum = d0 * d0 + d1 * d1 + d2 * d2 + d3 * d3;
            #pragma unroll
            for (int m = 1; m < 16; m <<= 1) vsum += __shfl_xor(vsum, m, 64);
            #pragma unroll
            for (int tt = 0; tt < 4; ++tt) {
                const int t = wv * 4 + tt;
                const float mu = __shfl(mug, tt * 16, 64);
                const float vv = __shfl(vsum, tt * 16, 64);
                const float rs = frsq(vv * 0.015625f + 1e-5f);   // variance = vsum/64
                const float a  = ky_lds[t * 68 + l];
                const float an = (a - mu) * rs * lngv + lnbv;
                const float rnew = res_reg[tt] + an;
                res_reg[tt] = rnew;
                cur_reg[tt] = rnew;
                a_lds[t * 64 + (((l >> 3) ^ (t & 7)) * 8) + (l & 7)] = f2bf(rnew);
            }
        }
        if (st < 2) { WRITE2(0, wr0, wr1); WRITE2(1, wr2, wr3); WRITE2(2, wr4, wr5); }
    }

    // ---------------- head: leaky(res @ Wout + bout, 0.1), 5 output copies ----------------
    const float wo = Wout[l];
    const float bo = bout[0];
    #pragma unroll
    for (int tt = 0; tt < 4; ++tt)
        q_lds[(wv * 4 + tt) * 68 + l] = res_reg[tt] * wo;   // wave-private rows
    {
        const float4 pv = *reinterpret_cast<const float4*>(&q_lds[tg * 68 + ge * 4]);
        float p = pv.x + pv.y + pv.z + pv.w;
        #pragma unroll
        for (int m = 1; m < 16; m <<= 1) p += __shfl_xor(p, m, 64);
        if (ge == 0) {
            float o = p + bo;
            o = o >= 0.f ? o : 0.1f * o;
            #pragma unroll
            for (int c5 = 0; c5 < 5; ++c5)
                out[(size_t)c5 * NTOK + n0 + tg] = o;
        }
    }
}

extern "C" void kernel_launch(void* const* d_in, const int* in_sizes, int n_in,
                              void* d_out, int out_size, void* d_ws, size_t ws_size,
                              hipStream_t stream) {
    const float* x    = (const float*)d_in[0];
    const float* W1   = (const float*)d_in[1];
    const float* b1   = (const float*)d_in[2];
    const float* Wq   = (const float*)d_in[3];
    const float* bq   = (const float*)d_in[4];
    const float* Wk   = (const float*)d_in[5];
    const float* bk   = (const float*)d_in[6];
    const float* Wv   = (const float*)d_in[7];
    const float* bv   = (const float*)d_in[8];
    const float* Wf1  = (const float*)d_in[9];
    const float* bf1  = (const float*)d_in[10];
    const float* Wf2  = (const float*)d_in[11];
    const float* bf2  = (const float*)d_in[12];
    const float* lngp = (const float*)d_in[13];
    const float* lnbp = (const float*)d_in[14];
    const float* Wout = (const float*)d_in[15];
    const float* bout = (const float*)d_in[16];
    float* outp = (float*)d_out;
    unsigned short* wsb = (unsigned short*)d_ws;

    hipLaunchKernelGGL(prep_kernel, dim3(304), dim3(256), 0, stream,
                       W1, Wq, Wk, Wv, Wf1, Wf2, wsb);
    hipLaunchKernelGGL(tf3_kernel, dim3(NTOK / TB), dim3(256), 0, stream,
                       x, b1, bq, bk, bv, bf1, bf2, lngp, lnbp, Wout, bout,
                       (const unsigned short*)wsb, outp);
}